// Round 12
// baseline (178.322 us; speedup 1.0000x reference)
//
#include <hip/hip_runtime.h>
#include <hip/hip_bf16.h>

#define B_ 2
#define S_ 2048
#define DM_ 1024
#define H_ 16
#define HD_ 64
#define QKVLD 3072
#define WELT_ ((size_t)DM_ * DM_)

using bf16x8 = __attribute__((ext_vector_type(8))) short;
using f16x2  = __attribute__((ext_vector_type(2))) _Float16;
using f16x8  = __attribute__((ext_vector_type(8))) _Float16;
using f32x4  = __attribute__((ext_vector_type(4))) float;
using f32x16 = __attribute__((ext_vector_type(16))) float;

// async global->LDS, 16B per lane, wave-uniform LDS base (+lane*16 implicit)
#define GLOAD16(g, l) __builtin_amdgcn_global_load_lds( \
    (const __attribute__((address_space(1))) void*)(g), \
    (__attribute__((address_space(3))) void*)(l), 16, 0, 0)

// XOR swizzle for [*][64]-bf16 tiles (used by GEMM only)
__device__ __forceinline__ int swz128(int row, int bytecol) {
    return row * 128 + (bytecol ^ ((row & 7) << 4));
}

__device__ __forceinline__ ushort bf16_rne(float f) {
    uint b = __builtin_bit_cast(uint, f);
    b += 0x7FFF + ((b >> 16) & 1);
    return (ushort)(b >> 16);
}

__device__ __forceinline__ float bf16_to_f(ushort u) {
    return __builtin_bit_cast(float, (uint)u << 16);
}

__device__ __forceinline__ void pl32swap(uint& a, uint& b) {
    asm volatile("v_permlane32_swap_b32 %0, %1" : "+v"(a), "+v"(b));
}

// f32 pair -> packed f16 (v_cvt_pkrtz_f16_f32), bit_cast to our f16x2 type
__device__ __forceinline__ f16x2 cvt_pk_f16(float lo, float hi) {
    return __builtin_bit_cast(f16x2, __builtin_amdgcn_cvt_pkrtz(lo, hi));
}

// packed-f16 GELU (cubic erf fit, |err|<=~2e-3 on |x|<=2.6): all v_pk_*_f16.
__device__ __forceinline__ f16x2 gelu_h2(f16x2 x) {
    const f16x2 C3 = {(_Float16)-0.00074855f, (_Float16)-0.00074855f};
    const f16x2 C2 = {(_Float16)0.0146724f,   (_Float16)0.0146724f};
    const f16x2 C1 = {(_Float16)-0.1266945f,  (_Float16)-0.1266945f};
    const f16x2 C0 = {(_Float16)0.7966101f,   (_Float16)0.7966101f};
    const f16x2 ONE = {(_Float16)1.0f, (_Float16)1.0f};
    const f16x2 NEG = {(_Float16)-1.0f, (_Float16)-1.0f};
    const f16x2 HLF = {(_Float16)0.5f, (_Float16)0.5f};
    f16x2 u = x * x;
    f16x2 t = C3 * u + C2;
    t = t * u + C1;
    t = t * u + C0;
    f16x2 e = x * t;
    e = __builtin_elementwise_min(__builtin_elementwise_max(e, NEG), ONE);
    f16x2 hx = x * HLF;
    return hx * e + hx;
}

// ------ fused prep: x cast + 5 weight casts + bqkv + Wo-transpose + bcomb ------
__global__ __launch_bounds__(256) void prep_kernel(
    const float* __restrict__ x, __hip_bfloat16* __restrict__ xb,
    const float* __restrict__ Wq, const float* __restrict__ Wk, const float* __restrict__ Wv,
    const float* __restrict__ Wo, const float* __restrict__ Wg,
    const float* __restrict__ bq, const float* __restrict__ bk, const float* __restrict__ bv,
    const float* __restrict__ bo, const float* __restrict__ bg,
    const float* __restrict__ aw, __hip_bfloat16* __restrict__ Wall,
    __hip_bfloat16* __restrict__ Wcomb, __hip_bfloat16* __restrict__ Wot,
    float* __restrict__ bqkv, float* __restrict__ bcomb)
{
    __shared__ ushort stile[64][72];
    auto headw = [&](int h) {
        float mx = aw[0];
        for (int i = 1; i < H_; ++i) mx = fmaxf(mx, aw[i]);
        float sm = 0.f;
        for (int i = 0; i < H_; ++i) sm += expf(aw[i] - mx);
        return expf(aw[h] - mx) / sm;
    };
    const int tid = threadIdx.x;
    int blk = blockIdx.x;
    if (blk < 4096) {                       // x cast
        int i = blk * 1024 + tid * 4;
        float4 v = *(const float4*)(x + i);
        ushort4 o = { bf16_rne(v.x), bf16_rne(v.y), bf16_rne(v.z), bf16_rne(v.w) };
        *(ushort4*)(xb + i) = o;
    } else if (blk < 9216) {                // 5 weight matrices
        blk -= 4096;
        int widx = blk >> 10;
        int row = blk & 1023;
        int off = row * 1024 + tid * 4;
        const float* src = widx == 0 ? Wq : widx == 1 ? Wk : widx == 2 ? Wv : widx == 3 ? Wo : Wg;
        float scale = widx == 0 ? 0.125f : 1.0f;
        if (widx == 2) scale = headw(row >> 6);   // fold softmax(aw) into Wv rows
        __hip_bfloat16* dst = (widx == 3) ? Wcomb
                            : Wall + (size_t)(widx == 4 ? 3 : widx) * WELT_;
        float4 v = *(const float4*)(src + off);
        ushort4 o = { bf16_rne(v.x * scale), bf16_rne(v.y * scale),
                      bf16_rne(v.z * scale), bf16_rne(v.w * scale) };
        *(ushort4*)(dst + off) = o;
    } else if (blk < 9228) {                // qkv bias concat
        int i = (blk - 9216) * 256 + tid;
        if (i < 3 * DM_) {
            float v;
            if (i < DM_) v = bq[i] * 0.125f;
            else if (i < 2 * DM_) v = bk[i - DM_];
            else v = bv[i - 2 * DM_] * headw((i - 2 * DM_) >> 6);
            bqkv[i] = v;
        }
    } else if (blk < 9484) {                // Wo (f32) -> Wot (bf16, transposed)
        int idx = blk - 9228;
        const int c0 = (idx & 15) * 64, r0 = (idx >> 4) * 64;
#pragma unroll
        for (int c = tid; c < 1024; c += 256) {
            int row = c >> 4, cg = c & 15;
            float4 v = *(const float4*)(Wo + (size_t)(r0 + row) * 1024 + c0 + cg * 4);
            stile[row][cg * 4 + 0] = bf16_rne(v.x);
            stile[row][cg * 4 + 1] = bf16_rne(v.y);
            stile[row][cg * 4 + 2] = bf16_rne(v.z);
            stile[row][cg * 4 + 3] = bf16_rne(v.w);
        }
        __syncthreads();
#pragma unroll
        for (int c = tid; c < 512; c += 256) {
            int d = c >> 3, tg = c & 7;
            union { ushort u[8]; float4 v; } tmp;
#pragma unroll
            for (int j = 0; j < 8; ++j) tmp.u[j] = stile[tg * 8 + j][d];
            *(float4*)(Wot + (size_t)(c0 + d) * 1024 + r0 + tg * 8) = tmp.v;
        }
    } else {                                // bcomb = [bo | bg + Wg@bo]
        int idx = blk - 9484;
        const int w = tid >> 6, lane = tid & 63;
        if (idx < 4) bcomb[idx * 256 + tid] = bo[idx * 256 + tid];
        const int row = idx * 4 + w;
        float s = 0.f;
        for (int k = lane; k < 1024; k += 64) s += Wg[row * 1024 + k] * bo[k];
#pragma unroll
        for (int off = 32; off > 0; off >>= 1) s += __shfl_down(s, off, 64);
        if (lane == 0) bcomb[1024 + row] = bg[row] + s;
    }
}

// -------- NT bf16 GEMM (128x128, gload_lds) with optional piggy-back 2nd GEMM --------
__global__ __launch_bounds__(256, 2) void gemm_nt_kernel(
    const __hip_bfloat16* __restrict__ A, int lda,
    const __hip_bfloat16* __restrict__ Bw, int ldb,
    const float* __restrict__ bias, float* __restrict__ Cf,
    __hip_bfloat16* __restrict__ Cb, int ldc, int K, int gx1, int nblk1,
    const __hip_bfloat16* __restrict__ A2, const __hip_bfloat16* __restrict__ B2,
    __hip_bfloat16* __restrict__ C2)
{
    __shared__ __align__(16) char smem[32768];
    const int tid = threadIdx.x;
    const int w = tid >> 6, lane = tid & 63, hi = lane >> 4, lo = lane & 15;
    const int wr = w >> 1, wc = w & 1;

    const int bid = blockIdx.x;
    const __hip_bfloat16 *Ap, *Bp;
    const float* bp;
    float* cf;
    __hip_bfloat16* cb;
    int LDA, LDB, LDC, KK, bx, by;
    if (bid < nblk1) {
        bx = bid % gx1; by = bid / gx1;
        Ap = A; Bp = Bw; bp = bias; cf = Cf; cb = Cb;
        LDA = lda; LDB = ldb; LDC = ldc; KK = K;
    } else {
        int t2 = bid - nblk1;
        bx = t2 & 7; by = t2 >> 3;
        Ap = A2; Bp = B2; bp = nullptr; cf = nullptr; cb = C2;
        LDA = DM_; LDB = DM_; LDC = DM_; KK = DM_;
    }
    const int m0 = by * 128, n0 = bx * 128;

    const int srow = lane >> 3;
    const int scol = (lane & 7) ^ srow;
    const __hip_bfloat16* sbase;
    int sld;
    char* lbase;
    if (w < 2) {
        sbase = Ap + (size_t)(m0 + w * 64 + srow) * LDA + scol * 8;
        sld = LDA;
        lbase = smem + w * 8192;
    } else {
        sbase = Bp + (size_t)(n0 + (w - 2) * 64 + srow) * LDB + scol * 8;
        sld = LDB;
        lbase = smem + 16384 + (w - 2) * 8192;
    }

    f32x4 acc[4][4];
#pragma unroll
    for (int m = 0; m < 4; ++m)
#pragma unroll
        for (int n = 0; n < 4; ++n) acc[m][n] = (f32x4){0.f, 0.f, 0.f, 0.f};

    for (int k0 = 0; k0 < KK; k0 += 64) {
#pragma unroll
        for (int i = 0; i < 8; ++i)
            GLOAD16(sbase + (size_t)i * 8 * sld + k0, lbase + i * 1024);
        __syncthreads();
#pragma unroll
        for (int ks = 0; ks < 2; ++ks) {
            bf16x8 af[4], bfr[4];
#pragma unroll
            for (int m = 0; m < 4; ++m)
                af[m] = *(const bf16x8*)(smem + swz128(wr * 64 + m * 16 + lo, ks * 64 + hi * 16));
#pragma unroll
            for (int n = 0; n < 4; ++n)
                bfr[n] = *(const bf16x8*)(smem + 16384 + swz128(wc * 64 + n * 16 + lo, ks * 64 + hi * 16));
#pragma unroll
            for (int m = 0; m < 4; ++m)
#pragma unroll
                for (int n = 0; n < 4; ++n)
                    acc[m][n] = __builtin_amdgcn_mfma_f32_16x16x32_bf16(af[m], bfr[n], acc[m][n], 0, 0, 0);
        }
        __syncthreads();
    }

#pragma unroll
    for (int n = 0; n < 4; ++n) {
        int gc = n0 + wc * 64 + n * 16 + lo;
        float bz = bp ? bp[gc] : 0.f;
#pragma unroll
        for (int m = 0; m < 4; ++m) {
            int gr = m0 + wr * 64 + m * 16 + hi * 4;
#pragma unroll
            for (int r = 0; r < 4; ++r) {
                float v = acc[m][n][r] + bz;
                size_t o = (size_t)(gr + r) * LDC + gc;
                if (cf) cf[o] = v;
                if (cb) *(ushort*)(cb + o) = bf16_rne(v);
            }
        }
    }
}

// ------ V slice of QKV (bf16) -> Vt[B,H,HD,S] in f16 (hw pre-folded into Wv) ------
__global__ __launch_bounds__(256) void transpose_v_kernel(const __hip_bfloat16* __restrict__ QKV,
                                                          _Float16* __restrict__ Vt) {
    __shared__ __align__(16) ushort tile[64][80];
    const int tid = threadIdx.x;
    const int nt = S_ / 64;
    const int blk = blockIdx.x;
    const int t0 = (blk % nt) * 64;
    const int bh = blk / nt;
    const int h = bh % H_, b = bh / H_;
#pragma unroll
    for (int c = tid; c < 512; c += 256) {
        int row = c >> 3, cg = c & 7;
        float4 v = *(const float4*)(QKV + (size_t)(b * S_ + t0 + row) * QKVLD + 2 * DM_ + h * HD_ + cg * 8);
        *(float4*)(&tile[row][cg * 8]) = v;
    }
    __syncthreads();
#pragma unroll
    for (int c = tid; c < 512; c += 256) {
        int d = c >> 3, tg = c & 7;
        union { _Float16 h16[8]; float4 v; } tmp;
#pragma unroll
        for (int j = 0; j < 8; ++j)
            tmp.h16[j] = (_Float16)bf16_to_f(tile[tg * 8 + j][d]);
        *(float4*)(Vt + ((size_t)(b * H_ + h) * HD_ + d) * S_ + t0 + tg * 8) = tmp.v;
    }
}

// ---------------- fused attention: K direct-to-register, V via LDS ----------------
// 512 thr = 8 waves: wave (qg = w&3, th = w>>2): qg's 32 q-rows over th's 64-t
// half of each 128-t tile. K fragments loaded global->reg (L2-resident via XCD
// swizzle; same strided pattern staging used). V staged via gload_lds (2x16KB
// dbuf). LDS reads halved vs R11 (only V). cacc halves combined at the end.
__global__ __launch_bounds__(512) void attn_kernel(
    const __hip_bfloat16* __restrict__ QKV, const _Float16* __restrict__ Vt,
    __hip_bfloat16* __restrict__ ctx)
{
    __shared__ __align__(16) char lds[2][16384];  // [buf][ V 16KB ]

    const int tid = threadIdx.x;
    const int w = tid >> 6, lane = tid & 63;
    const int l31 = lane & 31, hi2 = lane >> 5;
    const int qg = w & 3, th = w >> 2;
    const int nq = S_ / 128;                      // 16
    int blk = blockIdx.x;
    blk = (blk & 7) * 64 + (blk >> 3);            // bijective XCD swizzle (512 % 8 == 0)
    const int q0 = (blk % nq) * 128;
    const int bh = blk / nq;
    const int h = bh % H_, b = bh / H_;

    // Q fragments (B-operand) for this wave's 32 q-rows
    bf16x8 qf[4];
    {
        const __hip_bfloat16* qrow = QKV + ((size_t)(b * S_ + q0 + qg * 32 + l31) * QKVLD + h * HD_);
#pragma unroll
        for (int ks = 0; ks < 4; ++ks)
            qf[ks] = *(const bf16x8*)(qrow + ks * 16 + hi2 * 8);
    }

    // K direct-load pointers: kp[tci] -> K[t0 + (th*2+tci)*32 + l31][h*64 + hi2*8]
    // ks-frags at +32B imm offsets; advance 128 t (786432 B) per iter.
    const char* kp0 = (const char*)(QKV
        + (size_t)(b * S_ + (th * 2 + 0) * 32 + l31) * QKVLD + DM_ + h * HD_ + hi2 * 8);
    const char* kp1 = kp0 + (size_t)32 * QKVLD * 2;

    // V staging: wave w stages frags {2w, 2w+1}; frag f holds
    // Vt[(f>>3)*32 + l31][t0 + (f&7)*16 + hi2*8 ..+8) at lds + f*1024 + lane*16.
    const char* sp[2];
    int loff[2];
#pragma unroll
    for (int j = 0; j < 2; ++j) {
        int f = w * 2 + j;
        sp[j] = (const char*)(Vt + ((size_t)((b * H_ + h) * HD_) + (f >> 3) * 32 + l31) * S_
                              + (f & 7) * 16 + hi2 * 8);
        loff[j] = f * 1024;
    }

#define STAGE(buf) do { \
    _Pragma("unroll") \
    for (int j = 0; j < 2; ++j) { \
        GLOAD16(sp[j], lds[buf] + loff[j]); \
        sp[j] += 256; \
    } } while (0)

    f32x16 cacc[2];
#pragma unroll
    for (int n = 0; n < 2; ++n)
#pragma unroll
        for (int r = 0; r < 16; ++r) cacc[n][r] = 0.f;

    STAGE(0);
    asm volatile("s_waitcnt vmcnt(0)" ::: "memory");
    __builtin_amdgcn_s_barrier();

    const int lane16 = lane * 16;
    const int NT = S_ / 128;                      // 16
    for (int t = 0; t < NT; ++t) {
        const int cur = t & 1;
        if (t + 1 < NT) STAGE(cur ^ 1);

        // issue this iter's 8 K fragment loads (global, L2-hit)
        bf16x8 kfa[4], kfb[4];
#pragma unroll
        for (int ks = 0; ks < 4; ++ks) {
            kfa[ks] = *(const bf16x8*)(kp0 + ks * 32);
            kfb[ks] = *(const bf16x8*)(kp1 + ks * 32);
        }
        kp0 += (size_t)128 * QKVLD * 2;
        kp1 += (size_t)128 * QKVLD * 2;

        __builtin_amdgcn_s_setprio(1);
#pragma unroll
        for (int tci = 0; tci < 2; ++tci) {
            const int tc = th * 2 + tci;          // this wave's 32-t chunk
            f32x16 sacc;
#pragma unroll
            for (int r = 0; r < 16; ++r) sacc[r] = 0.f;
#pragma unroll
            for (int ks = 0; ks < 4; ++ks) {
                bf16x8 kf = tci ? kfb[ks] : kfa[ks];
                sacc = __builtin_amdgcn_mfma_f32_32x32x16_bf16(kf, qf[ks], sacc, 0, 0, 0);
            }
            // packed f16 P-path: cvt_pkrtz pairs -> pk-f16 GELU -> permlane swap
            f16x2 P[8];
#pragma unroll
            for (int i = 0; i < 8; ++i)
                P[i] = gelu_h2(cvt_pk_f16(sacc[2 * i], sacc[2 * i + 1]));
            uint a0 = __builtin_bit_cast(uint, P[0]), b0 = __builtin_bit_cast(uint, P[2]);
            uint a1 = __builtin_bit_cast(uint, P[1]), b1 = __builtin_bit_cast(uint, P[3]);
            uint a2 = __builtin_bit_cast(uint, P[4]), b2 = __builtin_bit_cast(uint, P[6]);
            uint a3 = __builtin_bit_cast(uint, P[5]), b3 = __builtin_bit_cast(uint, P[7]);
            pl32swap(a0, b0); pl32swap(a1, b1); pl32swap(a2, b2); pl32swap(a3, b3);
            union { uint u[4]; f16x8 v; } pa0, pa1;
            pa0.u[0] = a0; pa0.u[1] = a1; pa0.u[2] = b0; pa0.u[3] = b1;
            pa1.u[0] = a2; pa1.u[1] = a3; pa1.u[2] = b2; pa1.u[3] = b3;
#pragma unroll
            for (int kc2 = 0; kc2 < 2; ++kc2) {
                int kc = tc * 2 + kc2;
                f16x8 pa = kc2 ? pa1.v : pa0.v;
#pragma unroll
                for (int n2 = 0; n2 < 2; ++n2) {
                    f16x8 vf = *(const f16x8*)(lds[cur] + (n2 * 8 + kc) * 1024 + lane16);
                    cacc[n2] = __builtin_amdgcn_mfma_f32_32x32x16_f16(pa, vf, cacc[n2], 0, 0, 0);
                }
            }
        }
        __builtin_amdgcn_s_setprio(0);
        asm volatile("s_waitcnt vmcnt(0)" ::: "memory");
        __builtin_amdgcn_s_barrier();
    }

    // combine t-halves: th=1 waves write partials; th=0 add + store.
    // layout: qg*8192 + val*256 + lane*4 -> bank = lane (conflict-free).
    char* red = (char*)lds;
    if (th == 1) {
#pragma unroll
        for (int n2 = 0; n2 < 2; ++n2)
#pragma unroll
            for (int r = 0; r < 16; ++r)
                *(float*)(red + qg * 8192 + (n2 * 16 + r) * 256 + lane * 4) = cacc[n2][r];
    }
    __syncthreads();
    if (th == 0) {
#pragma unroll
        for (int n2 = 0; n2 < 2; ++n2)
#pragma unroll
            for (int r = 0; r < 16; ++r) {
                float v = cacc[n2][r] +
                    *(const float*)(red + qg * 8192 + (n2 * 16 + r) * 256 + lane * 4);
                int qrow = (r & 3) + 8 * (r >> 2) + 4 * hi2;
                size_t o = (size_t)(b * S_ + q0 + qg * 32 + qrow) * DM_ + h * HD_ + n2 * 32 + l31;
                *(ushort*)(ctx + o) = bf16_rne(v);
            }
    }
#undef STAGE
}

// ---------------- gate mix + residual + LayerNorm (all-bf16 inputs) ----------------
__global__ __launch_bounds__(256) void epilogue_ln_kernel(
    const __hip_bfloat16* __restrict__ og, const __hip_bfloat16* __restrict__ xb,
    const float* __restrict__ gamma, const float* __restrict__ beta,
    float* __restrict__ y)
{
    const int row = blockIdx.x, tid = threadIdx.x;
    const size_t obase = (size_t)row * 2048 + tid * 4;
    const size_t xbase = (size_t)row * DM_ + tid * 4;
    ushort4 ob = *(const ushort4*)(og + obase);
    ushort4 gb = *(const ushort4*)(og + obase + 1024);
    ushort4 xv = *(const ushort4*)(xb + xbase);
    float yv[4];
    float s = 0.f, s2 = 0.f;
    const ushort* obp = (const ushort*)&ob;
    const ushort* gbp = (const ushort*)&gb;
    const ushort* xp  = (const ushort*)&xv;
#pragma unroll
    for (int j = 0; j < 4; ++j) {
        float o = bf16_to_f(obp[j]), g = bf16_to_f(gbp[j]), xx = bf16_to_f(xp[j]);
        float gate = __builtin_amdgcn_rcpf(1.f + __expf(-g));
        float yy = gate * o + (1.f - gate) * xx + xx;
        yv[j] = yy;
        s += yy; s2 += yy * yy;
    }
    const int w = tid >> 6, lane = tid & 63;
#pragma unroll
    for (int off = 32; off > 0; off >>= 1) {
        s  += __shfl_down(s, off, 64);
        s2 += __shfl_down(s2, off, 64);
    }
    __shared__ float red[8];
    if (lane == 0) { red[w] = s; red[4 + w] = s2; }
    __syncthreads();
    s  = red[0] + red[1] + red[2] + red[3];
    s2 = red[4] + red[5] + red[6] + red[7];
    const float mu = s * (1.f / DM_);
    const float var = s2 * (1.f / DM_) - mu * mu;
    const float rstd = rsqrtf(var + 1e-5f);
    float4 outv;
#pragma unroll
    for (int j = 0; j < 4; ++j) {
        int col = tid * 4 + j;
        ((float*)&outv)[j] = (yv[j] - mu) * rstd * gamma[col] + beta[col];
    }
    *(float4*)(y + xbase) = outv;
}

extern "C" void kernel_launch(void* const* d_in, const int* in_sizes, int n_in,
                              void* d_out, int out_size, void* d_ws, size_t ws_size,
                              hipStream_t stream) {
    const float* x  = (const float*)d_in[0];
    const float* Wq = (const float*)d_in[1];
    const float* bq = (const float*)d_in[2];
    const float* Wk = (const float*)d_in[3];
    const float* bk = (const float*)d_in[4];
    const float* Wv = (const float*)d_in[5];
    const float* bv = (const float*)d_in[6];
    const float* Wo = (const float*)d_in[7];
    const float* bo = (const float*)d_in[8];
    const float* Wg = (const float*)d_in[9];
    const float* bg = (const float*)d_in[10];
    const float* aw = (const float*)d_in[11];
    const float* gamma = (const float*)d_in[12];
    const float* beta  = (const float*)d_in[13];

    char* ws = (char*)d_ws;
    size_t off = 0;
    auto alloc = [&](size_t bytes) -> char* {
        char* p = ws + off;
        off += (bytes + 255) & ~(size_t)255;
        return p;
    };
    const size_t NTOK = (size_t)B_ * S_;   // 4096
    const size_t NELT = NTOK * DM_;        // 4194304

    __hip_bfloat16* xb    = (__hip_bfloat16*)alloc(NELT * 2);
    __hip_bfloat16* Wall  = (__hip_bfloat16*)alloc(4 * WELT_ * 2);   // q,k,v,g
    __hip_bfloat16* Wot   = (__hip_bfloat16*)alloc(WELT_ * 2);
    __hip_bfloat16* Wcomb = (__hip_bfloat16*)alloc(2 * WELT_ * 2);   // [Wo; Wgo]
    float*          bqkv  = (float*)alloc(3 * DM_ * 4);
    float*          bcomb = (float*)alloc(2 * DM_ * 4);
    __hip_bfloat16* qkvb  = (__hip_bfloat16*)alloc(NTOK * QKVLD * 2);
    _Float16*       Vtb   = (_Float16*)alloc(NELT * 2);
    __hip_bfloat16* ctxb  = (__hip_bfloat16*)alloc(NELT * 2);
    __hip_bfloat16* ogb   = (__hip_bfloat16*)alloc(NTOK * 2048 * 2); // [out | gpre]

    // prep: x cast + weights + bqkv + Wot + bcomb  (9740 blocks)
    prep_kernel<<<9740, 256, 0, stream>>>(x, xb, Wq, Wk, Wv, Wo, Wg,
                                          bq, bk, bv, bo, bg, aw,
                                          Wall, Wcomb, Wot, bqkv, bcomb);

    // fused QKV projection (768 blocks) + piggy-backed Wgo = Wg@Wo (64 blocks)
    gemm_nt_kernel<<<768 + 64, 256, 0, stream>>>(
        xb, DM_, Wall, DM_, bqkv, nullptr, qkvb, QKVLD, DM_, 24, 768,
        Wall + 3 * WELT_, Wot, Wcomb + WELT_);

    transpose_v_kernel<<<B_ * H_ * (S_ / 64), 256, 0, stream>>>(qkvb, Vtb);
    attn_kernel<<<B_ * H_ * (S_ / 128), 512, 0, stream>>>(qkvb, Vtb, ctxb);

    // combined [out | gpre] = ctx @ [Wo; Wgo]^T + [bo; bg + Wg@bo]  (512 blocks)
    gemm_nt_kernel<<<512, 256, 0, stream>>>(
        ctxb, DM_, Wcomb, DM_, bcomb, nullptr, ogb, 2048, DM_, 16, 1 << 30,
        nullptr, nullptr, nullptr);

    epilogue_ln_kernel<<<(int)NTOK, 256, 0, stream>>>(ogb, xb, gamma, beta, (float*)d_out);
}

// Round 13
// 136.639 us; speedup vs baseline: 1.3051x; 1.3051x over previous
//
#include <hip/hip_runtime.h>
#include <hip/hip_bf16.h>

#define B_ 2
#define S_ 2048
#define DM_ 1024
#define H_ 16
#define HD_ 64
#define QKVLD 3072
#define WELT_ ((size_t)DM_ * DM_)

using bf16x8 = __attribute__((ext_vector_type(8))) short;
using f16x2  = __attribute__((ext_vector_type(2))) _Float16;
using f16x8  = __attribute__((ext_vector_type(8))) _Float16;
using f32x4  = __attribute__((ext_vector_type(4))) float;
using f32x16 = __attribute__((ext_vector_type(16))) float;

// async global->LDS, 16B per lane, wave-uniform LDS base (+lane*16 implicit)
#define GLOAD16(g, l) __builtin_amdgcn_global_load_lds( \
    (const __attribute__((address_space(1))) void*)(g), \
    (__attribute__((address_space(3))) void*)(l), 16, 0, 0)

// XOR swizzle for [*][64]-bf16 tiles (used by GEMM only)
__device__ __forceinline__ int swz128(int row, int bytecol) {
    return row * 128 + (bytecol ^ ((row & 7) << 4));
}

__device__ __forceinline__ ushort bf16_rne(float f) {
    uint b = __builtin_bit_cast(uint, f);
    b += 0x7FFF + ((b >> 16) & 1);
    return (ushort)(b >> 16);
}

__device__ __forceinline__ float bf16_to_f(ushort u) {
    return __builtin_bit_cast(float, (uint)u << 16);
}

__device__ __forceinline__ void pl32swap(uint& a, uint& b) {
    asm volatile("v_permlane32_swap_b32 %0, %1" : "+v"(a), "+v"(b));
}

// f32 pair -> packed f16 (v_cvt_pkrtz_f16_f32), bit_cast to our f16x2 type
__device__ __forceinline__ f16x2 cvt_pk_f16(float lo, float hi) {
    return __builtin_bit_cast(f16x2, __builtin_amdgcn_cvt_pkrtz(lo, hi));
}

// packed-f16 GELU (cubic erf fit, |err|<=~2e-3 on |x|<=2.6): all v_pk_*_f16.
__device__ __forceinline__ f16x2 gelu_h2(f16x2 x) {
    const f16x2 C3 = {(_Float16)-0.00074855f, (_Float16)-0.00074855f};
    const f16x2 C2 = {(_Float16)0.0146724f,   (_Float16)0.0146724f};
    const f16x2 C1 = {(_Float16)-0.1266945f,  (_Float16)-0.1266945f};
    const f16x2 C0 = {(_Float16)0.7966101f,   (_Float16)0.7966101f};
    const f16x2 ONE = {(_Float16)1.0f, (_Float16)1.0f};
    const f16x2 NEG = {(_Float16)-1.0f, (_Float16)-1.0f};
    const f16x2 HLF = {(_Float16)0.5f, (_Float16)0.5f};
    f16x2 u = x * x;
    f16x2 t = C3 * u + C2;
    t = t * u + C1;
    t = t * u + C0;
    f16x2 e = x * t;
    e = __builtin_elementwise_min(__builtin_elementwise_max(e, NEG), ONE);
    f16x2 hx = x * HLF;
    return hx * e + hx;
}

// ------ fused prep: x cast + 5 weight casts + bqkv + Wo-transpose + bcomb ------
__global__ __launch_bounds__(256) void prep_kernel(
    const float* __restrict__ x, __hip_bfloat16* __restrict__ xb,
    const float* __restrict__ Wq, const float* __restrict__ Wk, const float* __restrict__ Wv,
    const float* __restrict__ Wo, const float* __restrict__ Wg,
    const float* __restrict__ bq, const float* __restrict__ bk, const float* __restrict__ bv,
    const float* __restrict__ bo, const float* __restrict__ bg,
    const float* __restrict__ aw, __hip_bfloat16* __restrict__ Wall,
    __hip_bfloat16* __restrict__ Wcomb, __hip_bfloat16* __restrict__ Wot,
    float* __restrict__ bqkv, float* __restrict__ bcomb)
{
    __shared__ ushort stile[64][72];
    auto headw = [&](int h) {
        float mx = aw[0];
        for (int i = 1; i < H_; ++i) mx = fmaxf(mx, aw[i]);
        float sm = 0.f;
        for (int i = 0; i < H_; ++i) sm += expf(aw[i] - mx);
        return expf(aw[h] - mx) / sm;
    };
    const int tid = threadIdx.x;
    int blk = blockIdx.x;
    if (blk < 4096) {                       // x cast
        int i = blk * 1024 + tid * 4;
        float4 v = *(const float4*)(x + i);
        ushort4 o = { bf16_rne(v.x), bf16_rne(v.y), bf16_rne(v.z), bf16_rne(v.w) };
        *(ushort4*)(xb + i) = o;
    } else if (blk < 9216) {                // 5 weight matrices
        blk -= 4096;
        int widx = blk >> 10;
        int row = blk & 1023;
        int off = row * 1024 + tid * 4;
        const float* src = widx == 0 ? Wq : widx == 1 ? Wk : widx == 2 ? Wv : widx == 3 ? Wo : Wg;
        float scale = widx == 0 ? 0.125f : 1.0f;
        if (widx == 2) scale = headw(row >> 6);   // fold softmax(aw) into Wv rows
        __hip_bfloat16* dst = (widx == 3) ? Wcomb
                            : Wall + (size_t)(widx == 4 ? 3 : widx) * WELT_;
        float4 v = *(const float4*)(src + off);
        ushort4 o = { bf16_rne(v.x * scale), bf16_rne(v.y * scale),
                      bf16_rne(v.z * scale), bf16_rne(v.w * scale) };
        *(ushort4*)(dst + off) = o;
    } else if (blk < 9228) {                // qkv bias concat
        int i = (blk - 9216) * 256 + tid;
        if (i < 3 * DM_) {
            float v;
            if (i < DM_) v = bq[i] * 0.125f;
            else if (i < 2 * DM_) v = bk[i - DM_];
            else v = bv[i - 2 * DM_] * headw((i - 2 * DM_) >> 6);
            bqkv[i] = v;
        }
    } else if (blk < 9484) {                // Wo (f32) -> Wot (bf16, transposed)
        int idx = blk - 9228;
        const int c0 = (idx & 15) * 64, r0 = (idx >> 4) * 64;
#pragma unroll
        for (int c = tid; c < 1024; c += 256) {
            int row = c >> 4, cg = c & 15;
            float4 v = *(const float4*)(Wo + (size_t)(r0 + row) * 1024 + c0 + cg * 4);
            stile[row][cg * 4 + 0] = bf16_rne(v.x);
            stile[row][cg * 4 + 1] = bf16_rne(v.y);
            stile[row][cg * 4 + 2] = bf16_rne(v.z);
            stile[row][cg * 4 + 3] = bf16_rne(v.w);
        }
        __syncthreads();
#pragma unroll
        for (int c = tid; c < 512; c += 256) {
            int d = c >> 3, tg = c & 7;
            union { ushort u[8]; float4 v; } tmp;
#pragma unroll
            for (int j = 0; j < 8; ++j) tmp.u[j] = stile[tg * 8 + j][d];
            *(float4*)(Wot + (size_t)(c0 + d) * 1024 + r0 + tg * 8) = tmp.v;
        }
    } else {                                // bcomb = [bo | bg + Wg@bo]
        int idx = blk - 9484;
        const int w = tid >> 6, lane = tid & 63;
        if (idx < 4) bcomb[idx * 256 + tid] = bo[idx * 256 + tid];
        const int row = idx * 4 + w;
        float s = 0.f;
        for (int k = lane; k < 1024; k += 64) s += Wg[row * 1024 + k] * bo[k];
#pragma unroll
        for (int off = 32; off > 0; off >>= 1) s += __shfl_down(s, off, 64);
        if (lane == 0) bcomb[1024 + row] = bg[row] + s;
    }
}

// -------- NT bf16 GEMM (128x128, gload_lds) with optional piggy-back 2nd GEMM --------
__global__ __launch_bounds__(256, 2) void gemm_nt_kernel(
    const __hip_bfloat16* __restrict__ A, int lda,
    const __hip_bfloat16* __restrict__ Bw, int ldb,
    const float* __restrict__ bias, float* __restrict__ Cf,
    __hip_bfloat16* __restrict__ Cb, int ldc, int K, int gx1, int nblk1,
    const __hip_bfloat16* __restrict__ A2, const __hip_bfloat16* __restrict__ B2,
    __hip_bfloat16* __restrict__ C2)
{
    __shared__ __align__(16) char smem[32768];
    const int tid = threadIdx.x;
    const int w = tid >> 6, lane = tid & 63, hi = lane >> 4, lo = lane & 15;
    const int wr = w >> 1, wc = w & 1;

    const int bid = blockIdx.x;
    const __hip_bfloat16 *Ap, *Bp;
    const float* bp;
    float* cf;
    __hip_bfloat16* cb;
    int LDA, LDB, LDC, KK, bx, by;
    if (bid < nblk1) {
        bx = bid % gx1; by = bid / gx1;
        Ap = A; Bp = Bw; bp = bias; cf = Cf; cb = Cb;
        LDA = lda; LDB = ldb; LDC = ldc; KK = K;
    } else {
        int t2 = bid - nblk1;
        bx = t2 & 7; by = t2 >> 3;
        Ap = A2; Bp = B2; bp = nullptr; cf = nullptr; cb = C2;
        LDA = DM_; LDB = DM_; LDC = DM_; KK = DM_;
    }
    const int m0 = by * 128, n0 = bx * 128;

    const int srow = lane >> 3;
    const int scol = (lane & 7) ^ srow;
    const __hip_bfloat16* sbase;
    int sld;
    char* lbase;
    if (w < 2) {
        sbase = Ap + (size_t)(m0 + w * 64 + srow) * LDA + scol * 8;
        sld = LDA;
        lbase = smem + w * 8192;
    } else {
        sbase = Bp + (size_t)(n0 + (w - 2) * 64 + srow) * LDB + scol * 8;
        sld = LDB;
        lbase = smem + 16384 + (w - 2) * 8192;
    }

    f32x4 acc[4][4];
#pragma unroll
    for (int m = 0; m < 4; ++m)
#pragma unroll
        for (int n = 0; n < 4; ++n) acc[m][n] = (f32x4){0.f, 0.f, 0.f, 0.f};

    for (int k0 = 0; k0 < KK; k0 += 64) {
#pragma unroll
        for (int i = 0; i < 8; ++i)
            GLOAD16(sbase + (size_t)i * 8 * sld + k0, lbase + i * 1024);
        __syncthreads();
#pragma unroll
        for (int ks = 0; ks < 2; ++ks) {
            bf16x8 af[4], bfr[4];
#pragma unroll
            for (int m = 0; m < 4; ++m)
                af[m] = *(const bf16x8*)(smem + swz128(wr * 64 + m * 16 + lo, ks * 64 + hi * 16));
#pragma unroll
            for (int n = 0; n < 4; ++n)
                bfr[n] = *(const bf16x8*)(smem + 16384 + swz128(wc * 64 + n * 16 + lo, ks * 64 + hi * 16));
#pragma unroll
            for (int m = 0; m < 4; ++m)
#pragma unroll
                for (int n = 0; n < 4; ++n)
                    acc[m][n] = __builtin_amdgcn_mfma_f32_16x16x32_bf16(af[m], bfr[n], acc[m][n], 0, 0, 0);
        }
        __syncthreads();
    }

#pragma unroll
    for (int n = 0; n < 4; ++n) {
        int gc = n0 + wc * 64 + n * 16 + lo;
        float bz = bp ? bp[gc] : 0.f;
#pragma unroll
        for (int m = 0; m < 4; ++m) {
            int gr = m0 + wr * 64 + m * 16 + hi * 4;
#pragma unroll
            for (int r = 0; r < 4; ++r) {
                float v = acc[m][n][r] + bz;
                size_t o = (size_t)(gr + r) * LDC + gc;
                if (cf) cf[o] = v;
                if (cb) *(ushort*)(cb + o) = bf16_rne(v);
            }
        }
    }
}

// ------ V slice of QKV (bf16) -> Vt[B,H,HD,S] in f16 (hw pre-folded into Wv) ------
__global__ __launch_bounds__(256) void transpose_v_kernel(const __hip_bfloat16* __restrict__ QKV,
                                                          _Float16* __restrict__ Vt) {
    __shared__ __align__(16) ushort tile[64][80];
    const int tid = threadIdx.x;
    const int nt = S_ / 64;
    const int blk = blockIdx.x;
    const int t0 = (blk % nt) * 64;
    const int bh = blk / nt;
    const int h = bh % H_, b = bh / H_;
#pragma unroll
    for (int c = tid; c < 512; c += 256) {
        int row = c >> 3, cg = c & 7;
        float4 v = *(const float4*)(QKV + (size_t)(b * S_ + t0 + row) * QKVLD + 2 * DM_ + h * HD_ + cg * 8);
        *(float4*)(&tile[row][cg * 8]) = v;
    }
    __syncthreads();
#pragma unroll
    for (int c = tid; c < 512; c += 256) {
        int d = c >> 3, tg = c & 7;
        union { _Float16 h16[8]; float4 v; } tmp;
#pragma unroll
        for (int j = 0; j < 8; ++j)
            tmp.h16[j] = (_Float16)bf16_to_f(tile[tg * 8 + j][d]);
        *(float4*)(Vt + ((size_t)(b * H_ + h) * HD_ + d) * S_ + t0 + tg * 8) = tmp.v;
    }
}

// ---------------- fused attention: R11 structure, t-tile 64, 32KB LDS ----------------
// 512 thr = 8 waves: wave (qg = w&3, th = w>>2): qg's 32 q-rows over th's 32-t
// half of each 64-t tile. LDS 2 x (K 8KB | V 8KB) = 32KB -> 4 blocks/CU =
// 8 waves/SIMD (2x R11 occupancy), same per-CU instruction totals.
__global__ __launch_bounds__(512) void attn_kernel(
    const __hip_bfloat16* __restrict__ QKV, const _Float16* __restrict__ Vt,
    __hip_bfloat16* __restrict__ ctx)
{
    __shared__ __align__(16) char lds[2][16384];  // [buf][ K 8KB | V 8KB ]

    const int tid = threadIdx.x;
    const int w = tid >> 6, lane = tid & 63;
    const int l31 = lane & 31, hi2 = lane >> 5;
    const int qg = w & 3, th = w >> 2;
    const int nq = S_ / 128;                      // 16
    int blk = blockIdx.x;
    blk = (blk & 7) * 64 + (blk >> 3);            // bijective XCD swizzle (512 % 8 == 0)
    const int q0 = (blk % nq) * 128;
    const int bh = blk / nq;
    const int h = bh % H_, b = bh / H_;

    // Q fragments (B-operand) for this wave's 32 q-rows
    bf16x8 qf[4];
    {
        const __hip_bfloat16* qrow = QKV + ((size_t)(b * S_ + q0 + qg * 32 + l31) * QKVLD + h * HD_);
#pragma unroll
        for (int ks = 0; ks < 4; ++ks)
            qf[ks] = *(const bf16x8*)(qrow + ks * 16 + hi2 * 8);
    }

    // staging: waves 0..3 -> K frags {2w, 2w+1}; waves 4..7 -> V frags.
    // K frag f (f>>2 = 32t-chunk, f&3 = 16d-slice):
    //   lane l loads K[t0+(f>>2)*32+l31][(f&3)*16+hi2*8 ..+8) -> lds f*1024+lane*16
    // V frag f (f>>2 = 32d-chunk, f&3 = 16t-slice):
    //   lane l loads Vt[(f>>2)*32+l31][t0+(f&3)*16+hi2*8 ..+8) -> lds 8192+f*1024+lane*16
    const bool isK = (w < 4);
    const int f0 = (isK ? w : (w - 4)) * 2;
    const char* sp[2];
    int loff[2];
#pragma unroll
    for (int j = 0; j < 2; ++j) {
        int f = f0 + j;
        if (isK) {
            sp[j] = (const char*)(QKV + (size_t)(b * S_ + (f >> 2) * 32 + l31) * QKVLD + DM_ + h * HD_ + (f & 3) * 16 + hi2 * 8);
            loff[j] = f * 1024;
        } else {
            sp[j] = (const char*)(Vt + ((size_t)((b * H_ + h) * HD_) + (f >> 2) * 32 + l31) * S_ + (f & 3) * 16 + hi2 * 8);
            loff[j] = 8192 + f * 1024;
        }
    }
    const size_t tstep = isK ? (size_t)128 * QKVLD : (size_t)128;  // 64 t, in bytes

#define STAGE(buf) do { \
    _Pragma("unroll") \
    for (int j = 0; j < 2; ++j) { \
        GLOAD16(sp[j], lds[buf] + loff[j]); \
        sp[j] += tstep; \
    } } while (0)

    f32x16 cacc[2];
#pragma unroll
    for (int n = 0; n < 2; ++n)
#pragma unroll
        for (int r = 0; r < 16; ++r) cacc[n][r] = 0.f;

    STAGE(0);
    asm volatile("s_waitcnt vmcnt(0)" ::: "memory");
    __builtin_amdgcn_s_barrier();

    const int lane16 = lane * 16;
    const int NT = S_ / 64;                       // 32
    for (int t = 0; t < NT; ++t) {
        const int cur = t & 1;
        if (t + 1 < NT) STAGE(cur ^ 1);

        __builtin_amdgcn_s_setprio(1);
        // this wave's 32-t chunk: tc = th
        f32x16 sacc;
#pragma unroll
        for (int r = 0; r < 16; ++r) sacc[r] = 0.f;
#pragma unroll
        for (int ks = 0; ks < 4; ++ks) {
            bf16x8 kf = *(const bf16x8*)(lds[cur] + (th * 4 + ks) * 1024 + lane16);
            sacc = __builtin_amdgcn_mfma_f32_32x32x16_bf16(kf, qf[ks], sacc, 0, 0, 0);
        }
        // packed f16 P-path: cvt_pkrtz pairs -> pk-f16 GELU -> permlane swap
        f16x2 P[8];
#pragma unroll
        for (int i = 0; i < 8; ++i)
            P[i] = gelu_h2(cvt_pk_f16(sacc[2 * i], sacc[2 * i + 1]));
        uint a0 = __builtin_bit_cast(uint, P[0]), b0 = __builtin_bit_cast(uint, P[2]);
        uint a1 = __builtin_bit_cast(uint, P[1]), b1 = __builtin_bit_cast(uint, P[3]);
        uint a2 = __builtin_bit_cast(uint, P[4]), b2 = __builtin_bit_cast(uint, P[6]);
        uint a3 = __builtin_bit_cast(uint, P[5]), b3 = __builtin_bit_cast(uint, P[7]);
        pl32swap(a0, b0); pl32swap(a1, b1); pl32swap(a2, b2); pl32swap(a3, b3);
        union { uint u[4]; f16x8 v; } pa0, pa1;
        pa0.u[0] = a0; pa0.u[1] = a1; pa0.u[2] = b0; pa0.u[3] = b1;
        pa1.u[0] = a2; pa1.u[1] = a3; pa1.u[2] = b2; pa1.u[3] = b3;
#pragma unroll
        for (int kc2 = 0; kc2 < 2; ++kc2) {
            int kc = th * 2 + kc2;                // 16t-slice within the 64-t tile
            f16x8 pa = kc2 ? pa1.v : pa0.v;
#pragma unroll
            for (int n2 = 0; n2 < 2; ++n2) {
                f16x8 vf = *(const f16x8*)(lds[cur] + 8192 + (n2 * 4 + kc) * 1024 + lane16);
                cacc[n2] = __builtin_amdgcn_mfma_f32_32x32x16_f16(pa, vf, cacc[n2], 0, 0, 0);
            }
        }
        __builtin_amdgcn_s_setprio(0);
        asm volatile("s_waitcnt vmcnt(0)" ::: "memory");
        __builtin_amdgcn_s_barrier();
    }

    // combine t-halves: th=1 waves write partials; th=0 add + store.
    // layout: qg*8192 + val*256 + lane*4 -> bank = lane (conflict-free).
    char* red = (char*)lds;
    if (th == 1) {
#pragma unroll
        for (int n2 = 0; n2 < 2; ++n2)
#pragma unroll
            for (int r = 0; r < 16; ++r)
                *(float*)(red + qg * 8192 + (n2 * 16 + r) * 256 + lane * 4) = cacc[n2][r];
    }
    __syncthreads();
    if (th == 0) {
#pragma unroll
        for (int n2 = 0; n2 < 2; ++n2)
#pragma unroll
            for (int r = 0; r < 16; ++r) {
                float v = cacc[n2][r] +
                    *(const float*)(red + qg * 8192 + (n2 * 16 + r) * 256 + lane * 4);
                int qrow = (r & 3) + 8 * (r >> 2) + 4 * hi2;
                size_t o = (size_t)(b * S_ + q0 + qg * 32 + qrow) * DM_ + h * HD_ + n2 * 32 + l31;
                *(ushort*)(ctx + o) = bf16_rne(v);
            }
    }
#undef STAGE
}

// ---------------- gate mix + residual + LayerNorm (all-bf16 inputs) ----------------
__global__ __launch_bounds__(256) void epilogue_ln_kernel(
    const __hip_bfloat16* __restrict__ og, const __hip_bfloat16* __restrict__ xb,
    const float* __restrict__ gamma, const float* __restrict__ beta,
    float* __restrict__ y)
{
    const int row = blockIdx.x, tid = threadIdx.x;
    const size_t obase = (size_t)row * 2048 + tid * 4;
    const size_t xbase = (size_t)row * DM_ + tid * 4;
    ushort4 ob = *(const ushort4*)(og + obase);
    ushort4 gb = *(const ushort4*)(og + obase + 1024);
    ushort4 xv = *(const ushort4*)(xb + xbase);
    float yv[4];
    float s = 0.f, s2 = 0.f;
    const ushort* obp = (const ushort*)&ob;
    const ushort* gbp = (const ushort*)&gb;
    const ushort* xp  = (const ushort*)&xv;
#pragma unroll
    for (int j = 0; j < 4; ++j) {
        float o = bf16_to_f(obp[j]), g = bf16_to_f(gbp[j]), xx = bf16_to_f(xp[j]);
        float gate = __builtin_amdgcn_rcpf(1.f + __expf(-g));
        float yy = gate * o + (1.f - gate) * xx + xx;
        yv[j] = yy;
        s += yy; s2 += yy * yy;
    }
    const int w = tid >> 6, lane = tid & 63;
#pragma unroll
    for (int off = 32; off > 0; off >>= 1) {
        s  += __shfl_down(s, off, 64);
        s2 += __shfl_down(s2, off, 64);
    }
    __shared__ float red[8];
    if (lane == 0) { red[w] = s; red[4 + w] = s2; }
    __syncthreads();
    s  = red[0] + red[1] + red[2] + red[3];
    s2 = red[4] + red[5] + red[6] + red[7];
    const float mu = s * (1.f / DM_);
    const float var = s2 * (1.f / DM_) - mu * mu;
    const float rstd = rsqrtf(var + 1e-5f);
    float4 outv;
#pragma unroll
    for (int j = 0; j < 4; ++j) {
        int col = tid * 4 + j;
        ((float*)&outv)[j] = (yv[j] - mu) * rstd * gamma[col] + beta[col];
    }
    *(float4*)(y + xbase) = outv;
}

extern "C" void kernel_launch(void* const* d_in, const int* in_sizes, int n_in,
                              void* d_out, int out_size, void* d_ws, size_t ws_size,
                              hipStream_t stream) {
    const float* x  = (const float*)d_in[0];
    const float* Wq = (const float*)d_in[1];
    const float* bq = (const float*)d_in[2];
    const float* Wk = (const float*)d_in[3];
    const float* bk = (const float*)d_in[4];
    const float* Wv = (const float*)d_in[5];
    const float* bv = (const float*)d_in[6];
    const float* Wo = (const float*)d_in[7];
    const float* bo = (const float*)d_in[8];
    const float* Wg = (const float*)d_in[9];
    const float* bg = (const float*)d_in[10];
    const float* aw = (const float*)d_in[11];
    const float* gamma = (const float*)d_in[12];
    const float* beta  = (const float*)d_in[13];

    char* ws = (char*)d_ws;
    size_t off = 0;
    auto alloc = [&](size_t bytes) -> char* {
        char* p = ws + off;
        off += (bytes + 255) & ~(size_t)255;
        return p;
    };
    const size_t NTOK = (size_t)B_ * S_;   // 4096
    const size_t NELT = NTOK * DM_;        // 4194304

    __hip_bfloat16* xb    = (__hip_bfloat16*)alloc(NELT * 2);
    __hip_bfloat16* Wall  = (__hip_bfloat16*)alloc(4 * WELT_ * 2);   // q,k,v,g
    __hip_bfloat16* Wot   = (__hip_bfloat16*)alloc(WELT_ * 2);
    __hip_bfloat16* Wcomb = (__hip_bfloat16*)alloc(2 * WELT_ * 2);   // [Wo; Wgo]
    float*          bqkv  = (float*)alloc(3 * DM_ * 4);
    float*          bcomb = (float*)alloc(2 * DM_ * 4);
    __hip_bfloat16* qkvb  = (__hip_bfloat16*)alloc(NTOK * QKVLD * 2);
    _Float16*       Vtb   = (_Float16*)alloc(NELT * 2);
    __hip_bfloat16* ctxb  = (__hip_bfloat16*)alloc(NELT * 2);
    __hip_bfloat16* ogb   = (__hip_bfloat16*)alloc(NTOK * 2048 * 2); // [out | gpre]

    // prep: x cast + weights + bqkv + Wot + bcomb  (9740 blocks)
    prep_kernel<<<9740, 256, 0, stream>>>(x, xb, Wq, Wk, Wv, Wo, Wg,
                                          bq, bk, bv, bo, bg, aw,
                                          Wall, Wcomb, Wot, bqkv, bcomb);

    // fused QKV projection (768 blocks) + piggy-backed Wgo = Wg@Wo (64 blocks)
    gemm_nt_kernel<<<768 + 64, 256, 0, stream>>>(
        xb, DM_, Wall, DM_, bqkv, nullptr, qkvb, QKVLD, DM_, 24, 768,
        Wall + 3 * WELT_, Wot, Wcomb + WELT_);

    transpose_v_kernel<<<B_ * H_ * (S_ / 64), 256, 0, stream>>>(qkvb, Vtb);
    attn_kernel<<<B_ * H_ * (S_ / 128), 512, 0, stream>>>(qkvb, Vtb, ctxb);

    // combined [out | gpre] = ctx @ [Wo; Wgo]^T + [bo; bg + Wg@bo]  (512 blocks)
    gemm_nt_kernel<<<512, 256, 0, stream>>>(
        ctxb, DM_, Wcomb, DM_, bcomb, nullptr, ogb, 2048, DM_, 16, 1 << 30,
        nullptr, nullptr, nullptr);

    epilogue_ln_kernel<<<(int)NTOK, 256, 0, stream>>>(ogb, xb, gamma, beta, (float*)d_out);
}